// Round 7
// baseline (332.605 us; speedup 1.0000x reference)
//
#include <hip/hip_runtime.h>
#include <stdint.h>

typedef __bf16 bf16_t;
typedef __bf16 bf16x8 __attribute__((ext_vector_type(8)));
typedef float  f32x4  __attribute__((ext_vector_type(4)));

#define AS1 __attribute__((address_space(1)))
#define AS3 __attribute__((address_space(3)))

__device__ __forceinline__ void gld_lds16(const bf16_t* g, void* s) {
  // async global->LDS, 16 bytes per lane; HW dest = wave-uniform base + lane*16
  __builtin_amdgcn_global_load_lds((const AS1 uint32_t*)g, (AS3 uint32_t*)s, 16, 0, 0);
}

// ---------------------------------------------------------------------------
// 0) fp32 -> bf16 canonicalization, all 4 tensors in ONE dispatch.
// ---------------------------------------------------------------------------
__global__ __launch_bounds__(256) void convert_all_kernel(
    const float* __restrict__ X,  const float* __restrict__ Wq,
    const float* __restrict__ Wk, const float* __restrict__ Wv,
    bf16_t* __restrict__ Xc, bf16_t* __restrict__ Wqc,
    bf16_t* __restrict__ Wkc, bf16_t* __restrict__ Wvc) {
  const int blk = blockIdx.x;
  const float* src; bf16_t* dst; int base;
  if (blk < 4096)      { src = X;  dst = Xc;  base = 0;    }
  else if (blk < 4608) { src = Wq; dst = Wqc; base = 4096; }
  else if (blk < 5120) { src = Wk; dst = Wkc; base = 4608; }
  else                 { src = Wv; dst = Wvc; base = 5120; }
  const int i = ((blk - base) * 256 + threadIdx.x) * 8;
  const float4 a = ((const float4*)(src + i))[0];
  const float4 b = ((const float4*)(src + i))[1];
  bf16x8 v;
  v[0] = (bf16_t)a.x; v[1] = (bf16_t)a.y; v[2] = (bf16_t)a.z; v[3] = (bf16_t)a.w;
  v[4] = (bf16_t)b.x; v[5] = (bf16_t)b.y; v[6] = (bf16_t)b.z; v[7] = (bf16_t)b.w;
  *(bf16x8*)(dst + i) = v;
}

// ---------------------------------------------------------------------------
// Core: C[128x128] tile of A[M,K] * B[N,K]^T over k in [kBeg,kEnd), bf16 in,
// fp32 acc. 256 threads = 4 waves, 64x64 quadrant each. XOR-swizzled LDS
// (conflict-free, verified R4: SQ_LDS_BANK_CONFLICT 6.29M -> 0).
// ---------------------------------------------------------------------------
__device__ __forceinline__ void gemm_bt_core(
    const bf16_t* __restrict__ A, int lda,
    const bf16_t* __restrict__ B, int ldb,
    int m0, int n0, int kBeg, int kEnd,
    bf16_t* As, bf16_t* Bs, f32x4 acc[4][4])
{
  const int tid  = threadIdx.x;
  const int lane = tid & 63;
  const int wave = tid >> 6;
  const int wm = (wave >> 1) * 64;
  const int wn = (wave & 1) * 64;
  const int fr = lane & 15;          // m (A) / n (B) index within 16
  const int ck = lane >> 4;          // 16B k-chunk index (0..3)

  const int off0 = wave * 2048 + lane * 16;     // byte offset in 8KB tile
  const int row0 = wave * 32 + (lane >> 2);
  const int row1 = row0 + 16;
  const int kg   = ((lane & 3) ^ ((row0 >> 1) & 3)) * 8;

  int aoff[4], boff[4];
#pragma unroll
  for (int i = 0; i < 4; ++i) {
    const int ra = wm + i * 16 + fr;
    const int rb = wn + i * 16 + fr;
    aoff[i] = ra * 64 + ((ck ^ ((ra >> 1) & 3)) * 16);
    boff[i] = rb * 64 + ((ck ^ ((rb >> 1) & 3)) * 16);
  }

  for (int kt = kBeg; kt < kEnd; kt += 32) {
    __syncthreads();
    gld_lds16(A + (size_t)(m0 + row0) * lda + kt + kg, (char*)As + off0);
    gld_lds16(A + (size_t)(m0 + row1) * lda + kt + kg, (char*)As + off0 + 1024);
    gld_lds16(B + (size_t)(n0 + row0) * ldb + kt + kg, (char*)Bs + off0);
    gld_lds16(B + (size_t)(n0 + row1) * ldb + kt + kg, (char*)Bs + off0 + 1024);
    __syncthreads();

    bf16x8 af[4], bfv[4];
#pragma unroll
    for (int mi = 0; mi < 4; ++mi)
      af[mi] = *(const bf16x8*)((char*)As + aoff[mi]);
#pragma unroll
    for (int ni = 0; ni < 4; ++ni)
      bfv[ni] = *(const bf16x8*)((char*)Bs + boff[ni]);
#pragma unroll
    for (int mi = 0; mi < 4; ++mi)
#pragma unroll
      for (int ni = 0; ni < 4; ++ni)
        acc[mi][ni] = __builtin_amdgcn_mfma_f32_16x16x32_bf16(
            af[mi], bfv[ni], acc[mi][ni], 0, 0, 0);
  }
}

// ---------------------------------------------------------------------------
// 1) QKV projection: Out[z][8192,1024] = X[8192,1024] * W[z][1024,1024]^T
// ---------------------------------------------------------------------------
__global__ __launch_bounds__(256) void qkv_kernel(
    const bf16_t* __restrict__ X,
    const bf16_t* __restrict__ Wq, const bf16_t* __restrict__ Wk,
    const bf16_t* __restrict__ Wv,
    bf16_t* __restrict__ Q, bf16_t* __restrict__ K, bf16_t* __restrict__ V)
{
  __shared__ bf16_t As[128 * 32];
  __shared__ bf16_t Bs[128 * 32];
  const int m0 = blockIdx.x * 128;
  const int n0 = blockIdx.y * 128;
  const int z  = blockIdx.z;
  const bf16_t* W = (z == 0) ? Wq : (z == 1) ? Wk : Wv;
  bf16_t* Out     = (z == 0) ? Q  : (z == 1) ? K  : V;

  f32x4 acc[4][4] = {};
  gemm_bt_core(X, 1024, W, 1024, m0, n0, 0, 1024, As, Bs, acc);

  const int lane = threadIdx.x & 63;
  const int wave = threadIdx.x >> 6;
  const int wm = (wave >> 1) * 64, wn = (wave & 1) * 64;
#pragma unroll
  for (int mi = 0; mi < 4; ++mi)
#pragma unroll
    for (int r = 0; r < 4; ++r) {
      const int row = m0 + wm + mi * 16 + (lane >> 4) * 4 + r;
#pragma unroll
      for (int ni = 0; ni < 4; ++ni) {
        const int col = n0 + wn + ni * 16 + (lane & 15);
        Out[(size_t)row * 1024 + col] = (bf16_t)acc[mi][ni][r];
      }
    }
}

// ---------------------------------------------------------------------------
// 2) V transpose per batch: Vt[b][d][s] = V[b][s][d]
// ---------------------------------------------------------------------------
__global__ __launch_bounds__(256) void vt_kernel(
    const bf16_t* __restrict__ V, bf16_t* __restrict__ Vt)
{
  __shared__ bf16_t t[64][66];
  const int b  = blockIdx.z;
  const int s0 = blockIdx.x * 64;
  const int d0 = blockIdx.y * 64;
  const bf16_t* Vb = V  + (size_t)b * 2048 * 1024;
  bf16_t* Vtb      = Vt + (size_t)b * 1024 * 2048;
  const int c = threadIdx.x & 63, r4 = threadIdx.x >> 6;
#pragma unroll
  for (int i = 0; i < 16; ++i) {
    const int r = r4 + i * 4;
    t[r][c] = Vb[(size_t)(s0 + r) * 1024 + d0 + c];
  }
  __syncthreads();
#pragma unroll
  for (int i = 0; i < 16; ++i) {
    const int r = r4 + i * 4;
    Vtb[(size_t)(d0 + r) * 2048 + s0 + c] = t[c][r];
  }
}

// ---------------------------------------------------------------------------
// 3) Fused scores+exp: P[q,k] = exp((Q.K)/32) unnormalized, bf16; plus
// per-(ktile,row) denominators l. No max-subtraction needed: |s| <~ 6.
// Cross-wave row reduction through LDS (R6 fix, verified).
// ---------------------------------------------------------------------------
__global__ __launch_bounds__(256) void scores_exp_kernel(
    const bf16_t* __restrict__ Q, const bf16_t* __restrict__ K,
    bf16_t* __restrict__ P, float* __restrict__ partials, int b0)
{
  const int m0 = blockIdx.x * 128;   // q
  const int n0 = blockIdx.y * 128;   // k
  if (n0 > m0) return;               // fully masked tile
  __shared__ bf16_t As[128 * 32];
  __shared__ bf16_t Bs[128 * 32];
  __shared__ float rowsum[2][128];
  const int batch = b0 + blockIdx.z;
  const bf16_t* Qb = Q + (size_t)batch * 2048 * 1024;
  const bf16_t* Kb = K + (size_t)batch * 2048 * 1024;
  bf16_t* Pb = P + (size_t)blockIdx.z * 2048 * 2048;
  float* lp  = partials + ((size_t)blockIdx.z * 16 + (n0 >> 7)) * 2048;

  f32x4 acc[4][4] = {};
  gemm_bt_core(Qb, 1024, Kb, 1024, m0, n0, 0, 1024, As, Bs, acc);

  const int lane = threadIdx.x & 63;
  const int wave = threadIdx.x >> 6;
  const int wm = (wave >> 1) * 64, wn = (wave & 1) * 64;
  const float c = 0.04508422f;       // log2(e)/32
#pragma unroll
  for (int mi = 0; mi < 4; ++mi)
#pragma unroll
    for (int r = 0; r < 4; ++r) {
      const int lrow = wm + mi * 16 + (lane >> 4) * 4 + r;   // local row
      const int row  = m0 + lrow;
      float rs = 0.f;
#pragma unroll
      for (int ni = 0; ni < 4; ++ni) {
        const int col = n0 + wn + ni * 16 + (lane & 15);
        float p = exp2f(acc[mi][ni][r] * c);
        if (col > row) p = 0.f;      // only possible on diagonal tile
        const bf16_t pb = (bf16_t)p;
        Pb[(size_t)row * 2048 + col] = pb;
        rs += (float)pb;             // sum the rounded value pv will read
      }
      rs += __shfl_xor(rs, 1);
      rs += __shfl_xor(rs, 2);
      rs += __shfl_xor(rs, 4);
      rs += __shfl_xor(rs, 8);
      if ((lane & 15) == 0) rowsum[wave & 1][lrow] = rs;  // col-half partial
    }
  __syncthreads();
  if (threadIdx.x < 128)
    lp[m0 + threadIdx.x] = rowsum[0][threadIdx.x] + rowsum[1][threadIdx.x];
}

// ---------------------------------------------------------------------------
// 4) PV split-K: O_b[q,d] += (sum_{k in chunk} P[q,k]*Vt[d,k]) / l_q.
// R6: pv had 512 blocks with 16x work imbalance -> MfmaUtil 8%, Occ 12%.
// Now: per m-tile, k-range split into ceil(kEnd/512) even chunks (40 chunks
// per (d-tile,batch) slice -> grid 40x8x4 = 1280 uniform blocks, ~5/CU).
// Chunks accumulate into zero-initialized d_out via fp32 atomics; 1/l is
// chunk-independent (from Lp), so scaling distributes over the sum.
// ---------------------------------------------------------------------------
__global__ __launch_bounds__(256) void pv_splitk_kernel(
    const bf16_t* __restrict__ P, const bf16_t* __restrict__ Vt,
    const float* __restrict__ partials, float* __restrict__ out, int b0)
{
  __shared__ bf16_t As[128 * 32];
  __shared__ bf16_t Bs[128 * 32];
  // map blockIdx.x (0..39) -> (m-tile, chunk, nchunks)
  const int cid = blockIdx.x;
  int mt, ch, nch;
  if (cid < 4)       { mt = cid;               ch = 0;              nch = 1; }
  else if (cid < 12) { mt = 4 + (cid - 4) / 2; ch = (cid - 4) % 2;  nch = 2; }
  else if (cid < 24) { mt = 8 + (cid - 12) / 3; ch = (cid - 12) % 3; nch = 3; }
  else               { mt = 12 + (cid - 24) / 4; ch = (cid - 24) % 4; nch = 4; }
  const int m0   = mt * 128;                 // q
  const int kEnd = m0 + 128;
  const int sz   = ((kEnd / nch) + 31) & ~31;      // even chunks, 32-aligned
  const int k0   = ch * sz;
  const int k1   = (kEnd < k0 + sz) ? kEnd : k0 + sz;
  const int n0   = blockIdx.y * 128;         // d
  const int batch = b0 + blockIdx.z;
  const bf16_t* Pb  = P  + (size_t)blockIdx.z * 2048 * 2048;
  const bf16_t* Vtb = Vt + (size_t)batch * 1024 * 2048;

  f32x4 acc[4][4] = {};
  gemm_bt_core(Pb, 2048, Vtb, 2048, m0, n0, k0, k1, As, Bs, acc);

  const int lane = threadIdx.x & 63;
  const int wave = threadIdx.x >> 6;
  const int wm = (wave >> 1) * 64, wn = (wave & 1) * 64;
  const float* lp = partials + (size_t)blockIdx.z * 16 * 2048;
  float* ob = out + (size_t)batch * 2048 * 1024;
#pragma unroll
  for (int mi = 0; mi < 4; ++mi)
#pragma unroll
    for (int r = 0; r < 4; ++r) {
      const int row = m0 + wm + mi * 16 + (lane >> 4) * 4 + r;
      float l = 0.f;
      for (int t = 0; t <= mt; ++t) l += lp[t * 2048 + row];
      const float inv = 1.f / l;
#pragma unroll
      for (int ni = 0; ni < 4; ++ni) {
        const int col = n0 + wn + ni * 16 + (lane & 15);
        atomicAdd(&ob[(size_t)row * 1024 + col], acc[mi][ni][r] * inv);
      }
    }
}

// ---------------------------------------------------------------------------
extern "C" void kernel_launch(void* const* d_in, const int* in_sizes, int n_in,
                              void* d_out, int out_size, void* d_ws, size_t ws_size,
                              hipStream_t stream) {
  const float* X  = (const float*)d_in[0];
  const float* Wq = (const float*)d_in[1];
  const float* Wk = (const float*)d_in[2];
  const float* Wv = (const float*)d_in[3];
  float* out = (float*)d_out;
  char* ws = (char*)d_ws;

  const size_t NX = (size_t)4 * 2048 * 1024;   // 8.4M elements
  const size_t NW = (size_t)1024 * 1024;       // 1M elements
  const size_t QKV_BYTES = NX * 2;             // 16 MiB

  size_t  off  = 0;
  bf16_t* Xc   = (bf16_t*)(ws + off); off += NX * 2;
  bf16_t* Wqc  = (bf16_t*)(ws + off); off += NW * 2;
  bf16_t* Wkc  = (bf16_t*)(ws + off); off += NW * 2;
  bf16_t* Wvc  = (bf16_t*)(ws + off); off += NW * 2;
  bf16_t* Q    = (bf16_t*)(ws + off); off += QKV_BYTES;
  bf16_t* K    = (bf16_t*)(ws + off); off += QKV_BYTES;
  bf16_t* V    = (bf16_t*)(ws + off); off += QKV_BYTES;
  bf16_t* Vt   = (bf16_t*)(ws + off); off += QKV_BYTES;

  // per-batch: partials 16*2048 fp32 (128 KB) + P bf16 (8 MiB)
  const size_t L_B = (size_t)16 * 2048 * 4;
  const size_t P_B = (size_t)2048 * 2048 * 2;
  const int NB = (ws_size >= off + 4 * (L_B + P_B)) ? 4 : 1;
  float*  Lp = (float*)(ws + off);
  bf16_t* Pb = (bf16_t*)(ws + off + (size_t)NB * L_B);

  // d_out is poisoned before every call; pv accumulates atomically -> zero it
  hipMemsetAsync(out, 0, (size_t)out_size * 4, stream);

  convert_all_kernel<<<dim3(5632), 256, 0, stream>>>(X, Wq, Wk, Wv, Xc, Wqc, Wkc, Wvc);
  qkv_kernel<<<dim3(64, 8, 3), 256, 0, stream>>>(Xc, Wqc, Wkc, Wvc, Q, K, V);
  vt_kernel<<<dim3(32, 16, 4), 256, 0, stream>>>(V, Vt);
  for (int b0 = 0; b0 < 4; b0 += NB) {
    scores_exp_kernel<<<dim3(16, 16, NB), 256, 0, stream>>>(Q, K, Pb, Lp, b0);
    pv_splitk_kernel<<<dim3(40, 8, NB), 256, 0, stream>>>(Pb, Vt, Lp, out, b0);
  }
}

// Round 8
// 291.549 us; speedup vs baseline: 1.1408x; 1.1408x over previous
//
#include <hip/hip_runtime.h>
#include <stdint.h>

typedef __bf16 bf16_t;
typedef __bf16 bf16x8 __attribute__((ext_vector_type(8)));
typedef float  f32x4  __attribute__((ext_vector_type(4)));

#define AS1 __attribute__((address_space(1)))
#define AS3 __attribute__((address_space(3)))

__device__ __forceinline__ void gld_lds16(const bf16_t* g, void* s) {
  // async global->LDS, 16 bytes per lane; HW dest = wave-uniform base + lane*16
  __builtin_amdgcn_global_load_lds((const AS1 uint32_t*)g, (AS3 uint32_t*)s, 16, 0, 0);
}

// ---------------------------------------------------------------------------
// 0) fp32 -> bf16 canonicalization, all 4 tensors in ONE dispatch.
// ---------------------------------------------------------------------------
__global__ __launch_bounds__(256) void convert_all_kernel(
    const float* __restrict__ X,  const float* __restrict__ Wq,
    const float* __restrict__ Wk, const float* __restrict__ Wv,
    bf16_t* __restrict__ Xc, bf16_t* __restrict__ Wqc,
    bf16_t* __restrict__ Wkc, bf16_t* __restrict__ Wvc) {
  const int blk = blockIdx.x;
  const float* src; bf16_t* dst; int base;
  if (blk < 4096)      { src = X;  dst = Xc;  base = 0;    }
  else if (blk < 4608) { src = Wq; dst = Wqc; base = 4096; }
  else if (blk < 5120) { src = Wk; dst = Wkc; base = 4608; }
  else                 { src = Wv; dst = Wvc; base = 5120; }
  const int i = ((blk - base) * 256 + threadIdx.x) * 8;
  const float4 a = ((const float4*)(src + i))[0];
  const float4 b = ((const float4*)(src + i))[1];
  bf16x8 v;
  v[0] = (bf16_t)a.x; v[1] = (bf16_t)a.y; v[2] = (bf16_t)a.z; v[3] = (bf16_t)a.w;
  v[4] = (bf16_t)b.x; v[5] = (bf16_t)b.y; v[6] = (bf16_t)b.z; v[7] = (bf16_t)b.w;
  *(bf16x8*)(dst + i) = v;
}

// ---------------------------------------------------------------------------
// Core: C[128x128] tile of A[M,K] * B[N,K]^T over k in [kBeg,kEnd), bf16 in,
// fp32 acc. 256 threads = 4 waves, 64x64 quadrant each. XOR-swizzled LDS
// (conflict-free, verified R4). NOTE (R7 analysis): per iter each lane does
// 8 ds_read_b128 for 16 MFMAs -> LDS-throughput-bound at ~30-37% MfmaUtil;
// that plateau is structural to this core, consistent with m97.
// ---------------------------------------------------------------------------
__device__ __forceinline__ void gemm_bt_core(
    const bf16_t* __restrict__ A, int lda,
    const bf16_t* __restrict__ B, int ldb,
    int m0, int n0, int kBeg, int kEnd,
    bf16_t* As, bf16_t* Bs, f32x4 acc[4][4])
{
  const int tid  = threadIdx.x;
  const int lane = tid & 63;
  const int wave = tid >> 6;
  const int wm = (wave >> 1) * 64;
  const int wn = (wave & 1) * 64;
  const int fr = lane & 15;          // m (A) / n (B) index within 16
  const int ck = lane >> 4;          // 16B k-chunk index (0..3)

  const int off0 = wave * 2048 + lane * 16;     // byte offset in 8KB tile
  const int row0 = wave * 32 + (lane >> 2);
  const int row1 = row0 + 16;
  const int kg   = ((lane & 3) ^ ((row0 >> 1) & 3)) * 8;

  int aoff[4], boff[4];
#pragma unroll
  for (int i = 0; i < 4; ++i) {
    const int ra = wm + i * 16 + fr;
    const int rb = wn + i * 16 + fr;
    aoff[i] = ra * 64 + ((ck ^ ((ra >> 1) & 3)) * 16);
    boff[i] = rb * 64 + ((ck ^ ((rb >> 1) & 3)) * 16);
  }

  for (int kt = kBeg; kt < kEnd; kt += 32) {
    __syncthreads();
    gld_lds16(A + (size_t)(m0 + row0) * lda + kt + kg, (char*)As + off0);
    gld_lds16(A + (size_t)(m0 + row1) * lda + kt + kg, (char*)As + off0 + 1024);
    gld_lds16(B + (size_t)(n0 + row0) * ldb + kt + kg, (char*)Bs + off0);
    gld_lds16(B + (size_t)(n0 + row1) * ldb + kt + kg, (char*)Bs + off0 + 1024);
    __syncthreads();

    bf16x8 af[4], bfv[4];
#pragma unroll
    for (int mi = 0; mi < 4; ++mi)
      af[mi] = *(const bf16x8*)((char*)As + aoff[mi]);
#pragma unroll
    for (int ni = 0; ni < 4; ++ni)
      bfv[ni] = *(const bf16x8*)((char*)Bs + boff[ni]);
#pragma unroll
    for (int mi = 0; mi < 4; ++mi)
#pragma unroll
      for (int ni = 0; ni < 4; ++ni)
        acc[mi][ni] = __builtin_amdgcn_mfma_f32_16x16x32_bf16(
            af[mi], bfv[ni], acc[mi][ni], 0, 0, 0);
  }
}

// ---------------------------------------------------------------------------
// 1) QKV projection: Out[z][8192,1024] = X[8192,1024] * W[z][1024,1024]^T
// ---------------------------------------------------------------------------
__global__ __launch_bounds__(256) void qkv_kernel(
    const bf16_t* __restrict__ X,
    const bf16_t* __restrict__ Wq, const bf16_t* __restrict__ Wk,
    const bf16_t* __restrict__ Wv,
    bf16_t* __restrict__ Q, bf16_t* __restrict__ K, bf16_t* __restrict__ V)
{
  __shared__ bf16_t As[128 * 32];
  __shared__ bf16_t Bs[128 * 32];
  const int m0 = blockIdx.x * 128;
  const int n0 = blockIdx.y * 128;
  const int z  = blockIdx.z;
  const bf16_t* W = (z == 0) ? Wq : (z == 1) ? Wk : Wv;
  bf16_t* Out     = (z == 0) ? Q  : (z == 1) ? K  : V;

  f32x4 acc[4][4] = {};
  gemm_bt_core(X, 1024, W, 1024, m0, n0, 0, 1024, As, Bs, acc);

  const int lane = threadIdx.x & 63;
  const int wave = threadIdx.x >> 6;
  const int wm = (wave >> 1) * 64, wn = (wave & 1) * 64;
#pragma unroll
  for (int mi = 0; mi < 4; ++mi)
#pragma unroll
    for (int r = 0; r < 4; ++r) {
      const int row = m0 + wm + mi * 16 + (lane >> 4) * 4 + r;
#pragma unroll
      for (int ni = 0; ni < 4; ++ni) {
        const int col = n0 + wn + ni * 16 + (lane & 15);
        Out[(size_t)row * 1024 + col] = (bf16_t)acc[mi][ni][r];
      }
    }
}

// ---------------------------------------------------------------------------
// 2) V transpose per batch: Vt[b][d][s] = V[b][s][d]
// ---------------------------------------------------------------------------
__global__ __launch_bounds__(256) void vt_kernel(
    const bf16_t* __restrict__ V, bf16_t* __restrict__ Vt)
{
  __shared__ bf16_t t[64][66];
  const int b  = blockIdx.z;
  const int s0 = blockIdx.x * 64;
  const int d0 = blockIdx.y * 64;
  const bf16_t* Vb = V  + (size_t)b * 2048 * 1024;
  bf16_t* Vtb      = Vt + (size_t)b * 1024 * 2048;
  const int c = threadIdx.x & 63, r4 = threadIdx.x >> 6;
#pragma unroll
  for (int i = 0; i < 16; ++i) {
    const int r = r4 + i * 4;
    t[r][c] = Vb[(size_t)(s0 + r) * 1024 + d0 + c];
  }
  __syncthreads();
#pragma unroll
  for (int i = 0; i < 16; ++i) {
    const int r = r4 + i * 4;
    Vtb[(size_t)(d0 + r) * 2048 + s0 + c] = t[c][r];
  }
}

// ---------------------------------------------------------------------------
// 3) Fused scores+exp: P[q,k] = exp((Q.K)/32) unnormalized, bf16; plus
// per-(ktile,row) denominators l. No max-subtraction needed: |s| <~ 6.
// Cross-wave row reduction through LDS (R6 fix, verified).
// ---------------------------------------------------------------------------
__global__ __launch_bounds__(256) void scores_exp_kernel(
    const bf16_t* __restrict__ Q, const bf16_t* __restrict__ K,
    bf16_t* __restrict__ P, float* __restrict__ partials, int b0)
{
  const int m0 = blockIdx.x * 128;   // q
  const int n0 = blockIdx.y * 128;   // k
  if (n0 > m0) return;               // fully masked tile
  __shared__ bf16_t As[128 * 32];
  __shared__ bf16_t Bs[128 * 32];
  __shared__ float rowsum[2][128];
  const int batch = b0 + blockIdx.z;
  const bf16_t* Qb = Q + (size_t)batch * 2048 * 1024;
  const bf16_t* Kb = K + (size_t)batch * 2048 * 1024;
  bf16_t* Pb = P + (size_t)blockIdx.z * 2048 * 2048;
  float* lp  = partials + ((size_t)blockIdx.z * 16 + (n0 >> 7)) * 2048;

  f32x4 acc[4][4] = {};
  gemm_bt_core(Qb, 1024, Kb, 1024, m0, n0, 0, 1024, As, Bs, acc);

  const int lane = threadIdx.x & 63;
  const int wave = threadIdx.x >> 6;
  const int wm = (wave >> 1) * 64, wn = (wave & 1) * 64;
  const float c = 0.04508422f;       // log2(e)/32
#pragma unroll
  for (int mi = 0; mi < 4; ++mi)
#pragma unroll
    for (int r = 0; r < 4; ++r) {
      const int lrow = wm + mi * 16 + (lane >> 4) * 4 + r;   // local row
      const int row  = m0 + lrow;
      float rs = 0.f;
#pragma unroll
      for (int ni = 0; ni < 4; ++ni) {
        const int col = n0 + wn + ni * 16 + (lane & 15);
        float p = exp2f(acc[mi][ni][r] * c);
        if (col > row) p = 0.f;      // only possible on diagonal tile
        const bf16_t pb = (bf16_t)p;
        Pb[(size_t)row * 2048 + col] = pb;
        rs += (float)pb;             // sum the rounded value pv will read
      }
      rs += __shfl_xor(rs, 1);
      rs += __shfl_xor(rs, 2);
      rs += __shfl_xor(rs, 4);
      rs += __shfl_xor(rs, 8);
      if ((lane & 15) == 0) rowsum[wave & 1][lrow] = rs;  // col-half partial
    }
  __syncthreads();
  if (threadIdx.x < 128)
    lp[m0 + threadIdx.x] = rowsum[0][threadIdx.x] + rowsum[1][threadIdx.x];
}

// ---------------------------------------------------------------------------
// 4) PV paired: block (n, pair, b) computes q-tiles {pair, 15-pair} at d-tile
// n -> every block does exactly 17 k-tile passes (uniform work; R6's 16x
// imbalance gone) and owns its outputs exclusively (plain stores; R7's
// atomics cost ~40us and are reverted). O = (sum_k P*Vt)/l, fp32 out.
// ---------------------------------------------------------------------------
__global__ __launch_bounds__(256) void pv_paired_kernel(
    const bf16_t* __restrict__ P, const bf16_t* __restrict__ Vt,
    const float* __restrict__ partials, float* __restrict__ out, int b0)
{
  __shared__ bf16_t As[128 * 32];
  __shared__ bf16_t Bs[128 * 32];
  const int n0   = blockIdx.x * 128;        // d
  const int pair = blockIdx.y;              // 0..7
  const int batch = b0 + blockIdx.z;
  const bf16_t* Pb  = P  + (size_t)blockIdx.z * 2048 * 2048;
  const bf16_t* Vtb = Vt + (size_t)batch * 1024 * 2048;
  const float* lp = partials + (size_t)blockIdx.z * 16 * 2048;
  float* ob = out + (size_t)batch * 2048 * 1024;

  const int lane = threadIdx.x & 63;
  const int wave = threadIdx.x >> 6;
  const int wm = (wave >> 1) * 64, wn = (wave & 1) * 64;

#pragma unroll
  for (int t = 0; t < 2; ++t) {
    const int mt = t ? (15 - pair) : pair;
    const int m0 = mt * 128;
    const int kEnd = m0 + 128;

    f32x4 acc[4][4] = {};
    gemm_bt_core(Pb, 2048, Vtb, 2048, m0, n0, 0, kEnd, As, Bs, acc);

#pragma unroll
    for (int mi = 0; mi < 4; ++mi)
#pragma unroll
      for (int r = 0; r < 4; ++r) {
        const int row = m0 + wm + mi * 16 + (lane >> 4) * 4 + r;
        float l = 0.f;
        for (int kt = 0; kt <= mt; ++kt) l += lp[kt * 2048 + row];
        const float inv = 1.f / l;
#pragma unroll
        for (int ni = 0; ni < 4; ++ni) {
          const int col = n0 + wn + ni * 16 + (lane & 15);
          ob[(size_t)row * 1024 + col] = acc[mi][ni][r] * inv;
        }
      }
  }
}

// ---------------------------------------------------------------------------
extern "C" void kernel_launch(void* const* d_in, const int* in_sizes, int n_in,
                              void* d_out, int out_size, void* d_ws, size_t ws_size,
                              hipStream_t stream) {
  const float* X  = (const float*)d_in[0];
  const float* Wq = (const float*)d_in[1];
  const float* Wk = (const float*)d_in[2];
  const float* Wv = (const float*)d_in[3];
  float* out = (float*)d_out;
  char* ws = (char*)d_ws;

  const size_t NX = (size_t)4 * 2048 * 1024;   // 8.4M elements
  const size_t NW = (size_t)1024 * 1024;       // 1M elements
  const size_t QKV_BYTES = NX * 2;             // 16 MiB

  size_t  off  = 0;
  bf16_t* Xc   = (bf16_t*)(ws + off); off += NX * 2;
  bf16_t* Wqc  = (bf16_t*)(ws + off); off += NW * 2;
  bf16_t* Wkc  = (bf16_t*)(ws + off); off += NW * 2;
  bf16_t* Wvc  = (bf16_t*)(ws + off); off += NW * 2;
  bf16_t* Q    = (bf16_t*)(ws + off); off += QKV_BYTES;
  bf16_t* K    = (bf16_t*)(ws + off); off += QKV_BYTES;
  bf16_t* V    = (bf16_t*)(ws + off); off += QKV_BYTES;
  bf16_t* Vt   = (bf16_t*)(ws + off); off += QKV_BYTES;

  // per-batch: partials 16*2048 fp32 (128 KB) + P bf16 (8 MiB)
  const size_t L_B = (size_t)16 * 2048 * 4;
  const size_t P_B = (size_t)2048 * 2048 * 2;
  const int NB = (ws_size >= off + 4 * (L_B + P_B)) ? 4 : 1;
  float*  Lp = (float*)(ws + off);
  bf16_t* Pb = (bf16_t*)(ws + off + (size_t)NB * L_B);

  convert_all_kernel<<<dim3(5632), 256, 0, stream>>>(X, Wq, Wk, Wv, Xc, Wqc, Wkc, Wvc);
  qkv_kernel<<<dim3(64, 8, 3), 256, 0, stream>>>(Xc, Wqc, Wkc, Wvc, Q, K, V);
  vt_kernel<<<dim3(32, 16, 4), 256, 0, stream>>>(V, Vt);
  for (int b0 = 0; b0 < 4; b0 += NB) {
    scores_exp_kernel<<<dim3(16, 16, NB), 256, 0, stream>>>(Q, K, Pb, Lp, b0);
    pv_paired_kernel<<<dim3(8, 8, NB), 256, 0, stream>>>(Pb, Vt, Lp, out, b0);
  }
}

// Round 9
// 268.900 us; speedup vs baseline: 1.2369x; 1.0842x over previous
//
#include <hip/hip_runtime.h>
#include <stdint.h>

typedef __bf16 bf16_t;
typedef __bf16 bf16x8 __attribute__((ext_vector_type(8)));
typedef float  f32x4  __attribute__((ext_vector_type(4)));

#define AS1 __attribute__((address_space(1)))
#define AS3 __attribute__((address_space(3)))

__device__ __forceinline__ void gld_lds16(const bf16_t* g, void* s) {
  // async global->LDS, 16 bytes per lane; HW dest = wave-uniform base + lane*16
  __builtin_amdgcn_global_load_lds((const AS1 uint32_t*)g, (AS3 uint32_t*)s, 16, 0, 0);
}

// ---------------------------------------------------------------------------
// 0) fp32 -> bf16 canonicalization, all 4 tensors in ONE dispatch.
// ---------------------------------------------------------------------------
__global__ __launch_bounds__(256) void convert_all_kernel(
    const float* __restrict__ X,  const float* __restrict__ Wq,
    const float* __restrict__ Wk, const float* __restrict__ Wv,
    bf16_t* __restrict__ Xc, bf16_t* __restrict__ Wqc,
    bf16_t* __restrict__ Wkc, bf16_t* __restrict__ Wvc) {
  const int blk = blockIdx.x;
  const float* src; bf16_t* dst; int base;
  if (blk < 4096)      { src = X;  dst = Xc;  base = 0;    }
  else if (blk < 4608) { src = Wq; dst = Wqc; base = 4096; }
  else if (blk < 5120) { src = Wk; dst = Wkc; base = 4608; }
  else                 { src = Wv; dst = Wvc; base = 5120; }
  const int i = ((blk - base) * 256 + threadIdx.x) * 8;
  const float4 a = ((const float4*)(src + i))[0];
  const float4 b = ((const float4*)(src + i))[1];
  bf16x8 v;
  v[0] = (bf16_t)a.x; v[1] = (bf16_t)a.y; v[2] = (bf16_t)a.z; v[3] = (bf16_t)a.w;
  v[4] = (bf16_t)b.x; v[5] = (bf16_t)b.y; v[6] = (bf16_t)b.z; v[7] = (bf16_t)b.w;
  *(bf16x8*)(dst + i) = v;
}

// ---------------------------------------------------------------------------
// 128x128 core (qkv): C tile of A[M,K]*B[N,K]^T, k in [kBeg,kEnd). 4 waves,
// 64x64 quadrants. XOR-swizzled LDS (conflict-free, verified R4).
// ---------------------------------------------------------------------------
__device__ __forceinline__ void gemm_bt_core(
    const bf16_t* __restrict__ A, int lda,
    const bf16_t* __restrict__ B, int ldb,
    int m0, int n0, int kBeg, int kEnd,
    bf16_t* As, bf16_t* Bs, f32x4 acc[4][4])
{
  const int tid  = threadIdx.x;
  const int lane = tid & 63;
  const int wave = tid >> 6;
  const int wm = (wave >> 1) * 64;
  const int wn = (wave & 1) * 64;
  const int fr = lane & 15;
  const int ck = lane >> 4;

  const int off0 = wave * 2048 + lane * 16;
  const int row0 = wave * 32 + (lane >> 2);
  const int row1 = row0 + 16;
  const int kg   = ((lane & 3) ^ ((row0 >> 1) & 3)) * 8;

  int aoff[4], boff[4];
#pragma unroll
  for (int i = 0; i < 4; ++i) {
    const int ra = wm + i * 16 + fr;
    const int rb = wn + i * 16 + fr;
    aoff[i] = ra * 64 + ((ck ^ ((ra >> 1) & 3)) * 16);
    boff[i] = rb * 64 + ((ck ^ ((rb >> 1) & 3)) * 16);
  }

  for (int kt = kBeg; kt < kEnd; kt += 32) {
    __syncthreads();
    gld_lds16(A + (size_t)(m0 + row0) * lda + kt + kg, (char*)As + off0);
    gld_lds16(A + (size_t)(m0 + row1) * lda + kt + kg, (char*)As + off0 + 1024);
    gld_lds16(B + (size_t)(n0 + row0) * ldb + kt + kg, (char*)Bs + off0);
    gld_lds16(B + (size_t)(n0 + row1) * ldb + kt + kg, (char*)Bs + off0 + 1024);
    __syncthreads();

    bf16x8 af[4], bfv[4];
#pragma unroll
    for (int mi = 0; mi < 4; ++mi)
      af[mi] = *(const bf16x8*)((char*)As + aoff[mi]);
#pragma unroll
    for (int ni = 0; ni < 4; ++ni)
      bfv[ni] = *(const bf16x8*)((char*)Bs + boff[ni]);
#pragma unroll
    for (int mi = 0; mi < 4; ++mi)
#pragma unroll
      for (int ni = 0; ni < 4; ++ni)
        acc[mi][ni] = __builtin_amdgcn_mfma_f32_16x16x32_bf16(
            af[mi], bfv[ni], acc[mi][ni], 0, 0, 0);
  }
}

// ---------------------------------------------------------------------------
// 64x64 core (pv): A tile 64 rows, B tile 64 rows (4KB each). 4 waves in
// 2x2 of 32x32. 1 gld call per matrix per iter; same verified swizzle class.
// ---------------------------------------------------------------------------
__device__ __forceinline__ void gemm64_core(
    const bf16_t* __restrict__ A, int lda,
    const bf16_t* __restrict__ B, int ldb,
    int m0, int n0, int kBeg, int kEnd,
    bf16_t* As, bf16_t* Bs, f32x4 acc[2][2])
{
  const int lane = threadIdx.x & 63;
  const int wave = threadIdx.x >> 6;
  const int wm = (wave >> 1) * 32;
  const int wn = (wave & 1) * 32;
  const int fr = lane & 15;
  const int ck = lane >> 4;

  const int off0 = wave * 1024 + lane * 16;     // within 4KB tile
  const int row0 = wave * 16 + (lane >> 2);
  const int kg   = ((lane & 3) ^ ((row0 >> 1) & 3)) * 8;

  int aoff[2], boff[2];
#pragma unroll
  for (int i = 0; i < 2; ++i) {
    const int ra = wm + i * 16 + fr;
    const int rb = wn + i * 16 + fr;
    aoff[i] = ra * 64 + ((ck ^ ((ra >> 1) & 3)) * 16);
    boff[i] = rb * 64 + ((ck ^ ((rb >> 1) & 3)) * 16);
  }

  for (int kt = kBeg; kt < kEnd; kt += 32) {
    __syncthreads();
    gld_lds16(A + (size_t)(m0 + row0) * lda + kt + kg, (char*)As + off0);
    gld_lds16(B + (size_t)(n0 + row0) * ldb + kt + kg, (char*)Bs + off0);
    __syncthreads();

    bf16x8 af[2], bfv[2];
#pragma unroll
    for (int mi = 0; mi < 2; ++mi)
      af[mi] = *(const bf16x8*)((char*)As + aoff[mi]);
#pragma unroll
    for (int ni = 0; ni < 2; ++ni)
      bfv[ni] = *(const bf16x8*)((char*)Bs + boff[ni]);
#pragma unroll
    for (int mi = 0; mi < 2; ++mi)
#pragma unroll
      for (int ni = 0; ni < 2; ++ni)
        acc[mi][ni] = __builtin_amdgcn_mfma_f32_16x16x32_bf16(
            af[mi], bfv[ni], acc[mi][ni], 0, 0, 0);
  }
}

// ---------------------------------------------------------------------------
// 64x128 core (scores): A tile 64 rows (4KB), B tile 128 rows (8KB). 4 waves
// in 2x2 of 32x64.
// ---------------------------------------------------------------------------
__device__ __forceinline__ void gemm64x128_core(
    const bf16_t* __restrict__ A, int lda,
    const bf16_t* __restrict__ B, int ldb,
    int m0, int n0, int kEnd,
    bf16_t* As, bf16_t* Bs, f32x4 acc[2][4])
{
  const int lane = threadIdx.x & 63;
  const int wave = threadIdx.x >> 6;
  const int wm = (wave >> 1) * 32;
  const int wn = (wave & 1) * 64;
  const int fr = lane & 15;
  const int ck = lane >> 4;

  const int off0 = wave * 1024 + lane * 16;
  const int row0 = wave * 16 + (lane >> 2);
  const int row1 = row0 + 64;                   // B tile 2nd half
  const int kg   = ((lane & 3) ^ ((row0 >> 1) & 3)) * 8;  // (row+64) same swz

  int aoff[2], boff[4];
#pragma unroll
  for (int i = 0; i < 2; ++i) {
    const int ra = wm + i * 16 + fr;
    aoff[i] = ra * 64 + ((ck ^ ((ra >> 1) & 3)) * 16);
  }
#pragma unroll
  for (int i = 0; i < 4; ++i) {
    const int rb = wn + i * 16 + fr;
    boff[i] = rb * 64 + ((ck ^ ((rb >> 1) & 3)) * 16);
  }

  for (int kt = 0; kt < kEnd; kt += 32) {
    __syncthreads();
    gld_lds16(A + (size_t)(m0 + row0) * lda + kt + kg, (char*)As + off0);
    gld_lds16(B + (size_t)(n0 + row0) * ldb + kt + kg, (char*)Bs + off0);
    gld_lds16(B + (size_t)(n0 + row1) * ldb + kt + kg, (char*)Bs + off0 + 4096);
    __syncthreads();

    bf16x8 af[2], bfv[4];
#pragma unroll
    for (int mi = 0; mi < 2; ++mi)
      af[mi] = *(const bf16x8*)((char*)As + aoff[mi]);
#pragma unroll
    for (int ni = 0; ni < 4; ++ni)
      bfv[ni] = *(const bf16x8*)((char*)Bs + boff[ni]);
#pragma unroll
    for (int mi = 0; mi < 2; ++mi)
#pragma unroll
      for (int ni = 0; ni < 4; ++ni)
        acc[mi][ni] = __builtin_amdgcn_mfma_f32_16x16x32_bf16(
            af[mi], bfv[ni], acc[mi][ni], 0, 0, 0);
  }
}

// ---------------------------------------------------------------------------
// 1) QKV projection: Out[z][8192,1024] = X * W[z]^T (unchanged, 795 TF)
// ---------------------------------------------------------------------------
__global__ __launch_bounds__(256) void qkv_kernel(
    const bf16_t* __restrict__ X,
    const bf16_t* __restrict__ Wq, const bf16_t* __restrict__ Wk,
    const bf16_t* __restrict__ Wv,
    bf16_t* __restrict__ Q, bf16_t* __restrict__ K, bf16_t* __restrict__ V)
{
  __shared__ bf16_t As[128 * 32];
  __shared__ bf16_t Bs[128 * 32];
  const int m0 = blockIdx.x * 128;
  const int n0 = blockIdx.y * 128;
  const int z  = blockIdx.z;
  const bf16_t* W = (z == 0) ? Wq : (z == 1) ? Wk : Wv;
  bf16_t* Out     = (z == 0) ? Q  : (z == 1) ? K  : V;

  f32x4 acc[4][4] = {};
  gemm_bt_core(X, 1024, W, 1024, m0, n0, 0, 1024, As, Bs, acc);

  const int lane = threadIdx.x & 63;
  const int wave = threadIdx.x >> 6;
  const int wm = (wave >> 1) * 64, wn = (wave & 1) * 64;
#pragma unroll
  for (int mi = 0; mi < 4; ++mi)
#pragma unroll
    for (int r = 0; r < 4; ++r) {
      const int row = m0 + wm + mi * 16 + (lane >> 4) * 4 + r;
#pragma unroll
      for (int ni = 0; ni < 4; ++ni) {
        const int col = n0 + wn + ni * 16 + (lane & 15);
        Out[(size_t)row * 1024 + col] = (bf16_t)acc[mi][ni][r];
      }
    }
}

// ---------------------------------------------------------------------------
// 2) V transpose per batch: Vt[b][d][s] = V[b][s][d]
// ---------------------------------------------------------------------------
__global__ __launch_bounds__(256) void vt_kernel(
    const bf16_t* __restrict__ V, bf16_t* __restrict__ Vt)
{
  __shared__ bf16_t t[64][66];
  const int b  = blockIdx.z;
  const int s0 = blockIdx.x * 64;
  const int d0 = blockIdx.y * 64;
  const bf16_t* Vb = V  + (size_t)b * 2048 * 1024;
  bf16_t* Vtb      = Vt + (size_t)b * 1024 * 2048;
  const int c = threadIdx.x & 63, r4 = threadIdx.x >> 6;
#pragma unroll
  for (int i = 0; i < 16; ++i) {
    const int r = r4 + i * 4;
    t[r][c] = Vb[(size_t)(s0 + r) * 1024 + d0 + c];
  }
  __syncthreads();
#pragma unroll
  for (int i = 0; i < 16; ++i) {
    const int r = r4 + i * 4;
    Vtb[(size_t)(d0 + r) * 2048 + s0 + c] = t[c][r];
  }
}

// ---------------------------------------------------------------------------
// 3) Fused scores+exp, 64q x 128k tiles (R9: 1088 active blocks ~4.3/CU vs
// 544 ~2.1 -- latency-bound fix). P = exp((Q.K)/32) unnorm bf16 + lp sums.
// ---------------------------------------------------------------------------
__global__ __launch_bounds__(256) void scores_exp_kernel(
    const bf16_t* __restrict__ Q, const bf16_t* __restrict__ K,
    bf16_t* __restrict__ P, float* __restrict__ partials, int b0)
{
  const int kt = blockIdx.x;          // k-tile (128 wide)
  const int m0 = blockIdx.y * 64;     // q (64 rows)
  const int n0 = kt * 128;
  if (n0 > m0 + 63) return;           // fully masked
  __shared__ bf16_t As[64 * 32];
  __shared__ bf16_t Bs[128 * 32];
  __shared__ float rowsum[2][64];
  const int batch = b0 + blockIdx.z;
  const bf16_t* Qb = Q + (size_t)batch * 2048 * 1024;
  const bf16_t* Kb = K + (size_t)batch * 2048 * 1024;
  bf16_t* Pb = P + (size_t)blockIdx.z * 2048 * 2048;
  float* lp  = partials + ((size_t)blockIdx.z * 16 + kt) * 2048;

  f32x4 acc[2][4] = {};
  gemm64x128_core(Qb, 1024, Kb, 1024, m0, n0, 1024, As, Bs, acc);

  const int lane = threadIdx.x & 63;
  const int wave = threadIdx.x >> 6;
  const int wm = (wave >> 1) * 32, wn = (wave & 1) * 64;
  const float c = 0.04508422f;        // log2(e)/32
#pragma unroll
  for (int mi = 0; mi < 2; ++mi)
#pragma unroll
    for (int r = 0; r < 4; ++r) {
      const int lrow = wm + mi * 16 + (lane >> 4) * 4 + r;   // 0..63
      const int row  = m0 + lrow;
      float rs = 0.f;
#pragma unroll
      for (int ni = 0; ni < 4; ++ni) {
        const int col = n0 + wn + ni * 16 + (lane & 15);
        float p = exp2f(acc[mi][ni][r] * c);
        if (col > row) p = 0.f;
        const bf16_t pb = (bf16_t)p;
        Pb[(size_t)row * 2048 + col] = pb;
        rs += (float)pb;              // sum the rounded value pv reads
      }
      rs += __shfl_xor(rs, 1);
      rs += __shfl_xor(rs, 2);
      rs += __shfl_xor(rs, 4);
      rs += __shfl_xor(rs, 8);
      if ((lane & 15) == 0) rowsum[wave & 1][lrow] = rs;  // col-half partial
    }
  __syncthreads();
  if (threadIdx.x < 64)
    lp[m0 + threadIdx.x] = rowsum[0][threadIdx.x] + rowsum[1][threadIdx.x];
}

// ---------------------------------------------------------------------------
// 4) PV, 64q x 64d tiles, paired {mt, 31-mt} (uniform 66 k32-iters/block).
// R9: 1024 blocks ~4/CU, 8.5KB LDS (R8 was 256 blocks = 1/CU, latency-bound
// at MfmaUtil 8%). Plain exclusive stores (R7 atomics cost ~40us: banned).
// ---------------------------------------------------------------------------
__global__ __launch_bounds__(256) void pv_kernel(
    const bf16_t* __restrict__ P, const bf16_t* __restrict__ Vt,
    const float* __restrict__ partials, float* __restrict__ out, int b0)
{
  __shared__ bf16_t As[64 * 32];
  __shared__ bf16_t Bs[64 * 32];
  const int n0   = blockIdx.x * 64;         // d
  const int pair = blockIdx.y;              // 0..15
  const int batch = b0 + blockIdx.z;
  const bf16_t* Pb  = P  + (size_t)blockIdx.z * 2048 * 2048;
  const bf16_t* Vtb = Vt + (size_t)batch * 1024 * 2048;
  const float* lp = partials + (size_t)blockIdx.z * 16 * 2048;
  float* ob = out + (size_t)batch * 2048 * 1024;

  const int lane = threadIdx.x & 63;
  const int wave = threadIdx.x >> 6;
  const int wm = (wave >> 1) * 32, wn = (wave & 1) * 32;

#pragma unroll
  for (int t = 0; t < 2; ++t) {
    const int mt = t ? (31 - pair) : pair;  // q64-tile index
    const int m0 = mt * 64;
    const int kEnd = m0 + 64;

    f32x4 acc[2][2] = {};
    gemm64_core(Pb, 2048, Vtb, 2048, m0, n0, 0, kEnd, As, Bs, acc);

#pragma unroll
    for (int mi = 0; mi < 2; ++mi)
#pragma unroll
      for (int r = 0; r < 4; ++r) {
        const int row = m0 + wm + mi * 16 + (lane >> 4) * 4 + r;
        const int tmax = row >> 7;          // inclusive 128-k-tile index
        float l = 0.f;
        for (int kt = 0; kt <= tmax; ++kt) l += lp[kt * 2048 + row];
        const float inv = 1.f / l;
#pragma unroll
        for (int ni = 0; ni < 2; ++ni) {
          const int col = n0 + wn + ni * 16 + (lane & 15);
          ob[(size_t)row * 1024 + col] = acc[mi][ni][r] * inv;
        }
      }
  }
}

// ---------------------------------------------------------------------------
extern "C" void kernel_launch(void* const* d_in, const int* in_sizes, int n_in,
                              void* d_out, int out_size, void* d_ws, size_t ws_size,
                              hipStream_t stream) {
  const float* X  = (const float*)d_in[0];
  const float* Wq = (const float*)d_in[1];
  const float* Wk = (const float*)d_in[2];
  const float* Wv = (const float*)d_in[3];
  float* out = (float*)d_out;
  char* ws = (char*)d_ws;

  const size_t NX = (size_t)4 * 2048 * 1024;   // 8.4M elements
  const size_t NW = (size_t)1024 * 1024;       // 1M elements
  const size_t QKV_BYTES = NX * 2;             // 16 MiB

  size_t  off  = 0;
  bf16_t* Xc   = (bf16_t*)(ws + off); off += NX * 2;
  bf16_t* Wqc  = (bf16_t*)(ws + off); off += NW * 2;
  bf16_t* Wkc  = (bf16_t*)(ws + off); off += NW * 2;
  bf16_t* Wvc  = (bf16_t*)(ws + off); off += NW * 2;
  bf16_t* Q    = (bf16_t*)(ws + off); off += QKV_BYTES;
  bf16_t* K    = (bf16_t*)(ws + off); off += QKV_BYTES;
  bf16_t* V    = (bf16_t*)(ws + off); off += QKV_BYTES;
  bf16_t* Vt   = (bf16_t*)(ws + off); off += QKV_BYTES;

  // per-batch: partials 16*2048 fp32 (128 KB) + P bf16 (8 MiB)
  const size_t L_B = (size_t)16 * 2048 * 4;
  const size_t P_B = (size_t)2048 * 2048 * 2;
  const int NB = (ws_size >= off + 4 * (L_B + P_B)) ? 4 : 1;
  float*  Lp = (float*)(ws + off);
  bf16_t* Pb = (bf16_t*)(ws + off + (size_t)NB * L_B);

  convert_all_kernel<<<dim3(5632), 256, 0, stream>>>(X, Wq, Wk, Wv, Xc, Wqc, Wkc, Wvc);
  qkv_kernel<<<dim3(64, 8, 3), 256, 0, stream>>>(Xc, Wqc, Wkc, Wvc, Q, K, V);
  vt_kernel<<<dim3(32, 16, 4), 256, 0, stream>>>(V, Vt);
  for (int b0 = 0; b0 < 4; b0 += NB) {
    scores_exp_kernel<<<dim3(16, 32, NB), 256, 0, stream>>>(Q, K, Pb, Lp, b0);
    pv_kernel<<<dim3(16, 16, NB), 256, 0, stream>>>(Pb, Vt, Lp, out, b0);
  }
}